// Round 1
// baseline (184.414 us; speedup 1.0000x reference)
//
#include <hip/hip_runtime.h>
#include <math.h>

#define B 64
#define N 16384
#define MDIM 64
#define DDIM 512
#define EPSF 1e-16f

// ws float layout
#define K_OFF      0                      // B*64
#define SCAL_OFF   (B*64)                 // B*8: kn,beta,g,s0,s1,s2,gamma,pad
#define SCORE_OFF  (SCAL_OFF + B*8)       // B*N
#define PART_OFF   (SCORE_OFF + B*N)      // B*32*64

// ---------- K1: o = c@W.T + b, activations ----------
__global__ __launch_bounds__(256) void k1(const float* __restrict__ c,
                                          const float* __restrict__ W,
                                          const float* __restrict__ bias,
                                          float* __restrict__ ws) {
    int b = blockIdx.x;
    __shared__ float cs[DDIM];
    __shared__ float osh[72];
    int tid = threadIdx.x;
    for (int i = tid; i < DDIM; i += 256) cs[i] = c[b * DDIM + i];
    __syncthreads();
    int wave = tid >> 6, lane = tid & 63;
    for (int j = wave; j < MDIM + 6; j += 4) {
        const float* wr = W + (size_t)j * DDIM;
        float sum = 0.f;
        for (int d = lane; d < DDIM; d += 64) sum += cs[d] * wr[d];
        for (int off = 32; off > 0; off >>= 1) sum += __shfl_xor(sum, off);
        if (lane == 0) osh[j] = sum + bias[j];
    }
    __syncthreads();
    if (tid < 64) ws[K_OFF + b * 64 + tid] = osh[tid];
    if (wave == 0) {
        float v = osh[lane];
        float sq = v * v;
        for (int off = 32; off > 0; off >>= 1) sq += __shfl_xor(sq, off);
        if (lane == 0) {
            float kn = sqrtf(sq);
            float ob = osh[64], og = osh[65], os0 = osh[66], os1 = osh[67],
                  os2 = osh[68], ogm = osh[69];
            float beta  = fmaxf(ob, 0.f) + log1pf(expf(-fabsf(ob)));
            float g     = 1.f / (1.f + expf(-og));
            float mx    = fmaxf(os0, fmaxf(os1, os2));
            float e0 = expf(os0 - mx), e1 = expf(os1 - mx), e2 = expf(os2 - mx);
            float es = e0 + e1 + e2;
            float gamma = 1.f + fmaxf(ogm, 0.f) + log1pf(expf(-fabsf(ogm)));
            float* sc = ws + SCAL_OFF + b * 8;
            sc[0] = kn; sc[1] = beta; sc[2] = g;
            sc[3] = e0 / es; sc[4] = e1 / es; sc[5] = e2 / es;
            sc[6] = gamma;
        }
    }
}

// ---------- K2: score[b,n] = beta * dot(k, mem_row) / (kn*||mem_row|| + eps) ----------
__global__ __launch_bounds__(256) void k2(const float* __restrict__ mem,
                                          float* __restrict__ ws) {
    int b = blockIdx.x >> 5, chunk = blockIdx.x & 31;
    __shared__ float ks[64];
    __shared__ float kb[2];
    int tid = threadIdx.x;
    if (tid < 64) ks[tid] = ws[K_OFF + b * 64 + tid];
    if (tid == 64) kb[0] = ws[SCAL_OFF + b * 8 + 0];
    if (tid == 65) kb[1] = ws[SCAL_OFF + b * 8 + 1];
    __syncthreads();
    float kn = kb[0], beta = kb[1];
    int grp = tid >> 4, ll = tid & 15;
    float k0 = ks[ll * 4], k1v = ks[ll * 4 + 1], k2v = ks[ll * 4 + 2], k3v = ks[ll * 4 + 3];
    int row0 = chunk * 512;
    for (int it = 0; it < 32; ++it) {
        int row = row0 + it * 16 + grp;
        float4 v = *reinterpret_cast<const float4*>(
            mem + ((size_t)b * N + row) * MDIM + ll * 4);
        float dot = v.x * k0 + v.y * k1v + v.z * k2v + v.w * k3v;
        float sq  = v.x * v.x + v.y * v.y + v.z * v.z + v.w * v.w;
        for (int off = 8; off > 0; off >>= 1) {
            dot += __shfl_xor(dot, off);
            sq  += __shfl_xor(sq, off);
        }
        if (ll == 0) {
            float denom = kn * sqrtf(sq) + EPSF;
            ws[SCORE_OFF + (size_t)b * N + row] = beta * (dot / denom);
        }
    }
}

// ---------- KW: softmax over N, interpolate, shift, sharpen, normalize -> w ----------
__global__ __launch_bounds__(256) void kw(const float* __restrict__ w_prev,
                                          const float* __restrict__ ws,
                                          float* __restrict__ w_out) {
    int b = blockIdx.x;
    __shared__ float wg[N];
    __shared__ float red[4];
    int tid = threadIdx.x, wave = tid >> 6, lane = tid & 63;
    const float* sc = ws + SCORE_OFF + (size_t)b * N;
    const float* sl = ws + SCAL_OFF + b * 8;
    float g = sl[2], s0 = sl[3], s1 = sl[4], s2 = sl[5], gamma = sl[6];

    // pass 1: max
    float mx = -INFINITY;
    for (int i = tid; i < N; i += 256) mx = fmaxf(mx, sc[i]);
    for (int off = 32; off > 0; off >>= 1) mx = fmaxf(mx, __shfl_xor(mx, off));
    if (lane == 0) red[wave] = mx;
    __syncthreads();
    mx = fmaxf(fmaxf(red[0], red[1]), fmaxf(red[2], red[3]));
    __syncthreads();

    // pass 2: e = exp(sc - mx), sum
    float s = 0.f;
    for (int i = tid; i < N; i += 256) {
        float e = expf(sc[i] - mx);
        wg[i] = e;
        s += e;
    }
    for (int off = 32; off > 0; off >>= 1) s += __shfl_xor(s, off);
    if (lane == 0) red[wave] = s;
    __syncthreads();
    s = red[0] + red[1] + red[2] + red[3];
    float inv = 1.f / s;
    __syncthreads();

    // pass 3: w_g = g*w_c + (1-g)*w_prev (in place, own slots)
    const float* wp = w_prev + (size_t)b * N;
    for (int i = tid; i < N; i += 256)
        wg[i] = g * (wg[i] * inv) + (1.f - g) * wp[i];
    __syncthreads();

    // pass 4: sum of pow(w_t, gamma)
    float sp = 0.f;
    for (int i = tid; i < N; i += 256) {
        float wt = s0 * wg[(i - 1) & (N - 1)] + s1 * wg[i] + s2 * wg[(i + 1) & (N - 1)];
        sp += powf(wt, gamma);
    }
    for (int off = 32; off > 0; off >>= 1) sp += __shfl_xor(sp, off);
    if (lane == 0) red[wave] = sp;
    __syncthreads();
    float spTot = red[0] + red[1] + red[2] + red[3];
    float invp = 1.f / (spTot + EPSF);

    // pass 5: write normalized w
    for (int i = tid; i < N; i += 256) {
        float wt = s0 * wg[(i - 1) & (N - 1)] + s1 * wg[i] + s2 * wg[(i + 1) & (N - 1)];
        w_out[(size_t)b * N + i] = powf(wt, gamma) * invp;
    }
}

// ---------- KR: partial r = sum_n w[n] * mem[n, :] ----------
__global__ __launch_bounds__(256) void kr(const float* __restrict__ mem,
                                          const float* __restrict__ w,
                                          float* __restrict__ part) {
    int b = blockIdx.x >> 5, chunk = blockIdx.x & 31;
    int tid = threadIdx.x, grp = tid >> 4, ll = tid & 15;
    float4 acc = make_float4(0.f, 0.f, 0.f, 0.f);
    int row0 = chunk * 512;
    for (int it = 0; it < 32; ++it) {
        int row = row0 + it * 16 + grp;
        float wv = w[(size_t)b * N + row];
        float4 v = *reinterpret_cast<const float4*>(
            mem + ((size_t)b * N + row) * MDIM + ll * 4);
        acc.x += wv * v.x; acc.y += wv * v.y; acc.z += wv * v.z; acc.w += wv * v.w;
    }
    __shared__ float lds[16][64];
    lds[grp][ll * 4 + 0] = acc.x;
    lds[grp][ll * 4 + 1] = acc.y;
    lds[grp][ll * 4 + 2] = acc.z;
    lds[grp][ll * 4 + 3] = acc.w;
    __syncthreads();
    if (tid < 64) {
        float sacc = 0.f;
        for (int gi = 0; gi < 16; ++gi) sacc += lds[gi][tid];
        part[(size_t)blockIdx.x * 64 + tid] = sacc;
    }
}

// ---------- KRR: reduce partials -> r ----------
__global__ __launch_bounds__(64) void krr(const float* __restrict__ part,
                                          float* __restrict__ r) {
    int b = blockIdx.x, m = threadIdx.x;
    float s = 0.f;
    for (int c = 0; c < 32; ++c) s += part[((size_t)b * 32 + c) * 64 + m];
    r[b * 64 + m] = s;
}

extern "C" void kernel_launch(void* const* d_in, const int* in_sizes, int n_in,
                              void* d_out, int out_size, void* d_ws, size_t ws_size,
                              hipStream_t stream) {
    const float* c      = (const float*)d_in[0];
    const float* w_prev = (const float*)d_in[1];
    const float* mem    = (const float*)d_in[2];
    const float* W      = (const float*)d_in[3];
    const float* bias   = (const float*)d_in[4];
    float* out = (float*)d_out;
    float* r_out = out;                 // B*M
    float* w_out = out + B * MDIM;      // B*N
    float* ws = (float*)d_ws;

    k1<<<B, 256, 0, stream>>>(c, W, bias, ws);
    k2<<<B * 32, 256, 0, stream>>>(mem, ws);
    kw<<<B, 256, 0, stream>>>(w_prev, ws, w_out);
    kr<<<B * 32, 256, 0, stream>>>(mem, w_out, ws + PART_OFF);
    krr<<<B, 64, 0, stream>>>(ws + PART_OFF, r_out);
}

// Round 2
// 113.653 us; speedup vs baseline: 1.6226x; 1.6226x over previous
//
#include <hip/hip_runtime.h>
#include <math.h>

#define B 64
#define N 16384
#define MDIM 64
#define DDIM 512
#define EPSF 1e-16f

// ws float layout
#define K_OFF      0                      // B*64
#define SCAL_OFF   (B*64)                 // B*8: kn,beta,g,s0,s1,s2,gamma,pad
#define SCORE_OFF  (SCAL_OFF + B*8)       // B*N
#define PART_OFF   (SCORE_OFF + B*N)      // B*32*64

// 16-lane (DPP row) sum reduction: row_ror 8,4,2,1. All 16 lanes end with the sum.
__device__ __forceinline__ float rowsum16(float x) {
    float t;
    t = __int_as_float(__builtin_amdgcn_update_dpp(0, __float_as_int(x), 0x128, 0xF, 0xF, true)); x += t;
    t = __int_as_float(__builtin_amdgcn_update_dpp(0, __float_as_int(x), 0x124, 0xF, 0xF, true)); x += t;
    t = __int_as_float(__builtin_amdgcn_update_dpp(0, __float_as_int(x), 0x122, 0xF, 0xF, true)); x += t;
    t = __int_as_float(__builtin_amdgcn_update_dpp(0, __float_as_int(x), 0x121, 0xF, 0xF, true)); x += t;
    return x;
}

// ---------- K1: o = c@W.T + b, activations ----------
__global__ __launch_bounds__(256) void k1(const float* __restrict__ c,
                                          const float* __restrict__ W,
                                          const float* __restrict__ bias,
                                          float* __restrict__ ws) {
    int b = blockIdx.x;
    __shared__ float cs[DDIM];
    __shared__ float osh[72];
    int tid = threadIdx.x;
    for (int i = tid; i < DDIM; i += 256) cs[i] = c[b * DDIM + i];
    __syncthreads();
    int wave = tid >> 6, lane = tid & 63;
    for (int j = wave; j < MDIM + 6; j += 4) {
        const float* wr = W + (size_t)j * DDIM;
        float sum = 0.f;
        for (int d = lane; d < DDIM; d += 64) sum += cs[d] * wr[d];
        for (int off = 32; off > 0; off >>= 1) sum += __shfl_xor(sum, off);
        if (lane == 0) osh[j] = sum + bias[j];
    }
    __syncthreads();
    if (tid < 64) ws[K_OFF + b * 64 + tid] = osh[tid];
    if (wave == 0) {
        float v = osh[lane];
        float sq = v * v;
        for (int off = 32; off > 0; off >>= 1) sq += __shfl_xor(sq, off);
        if (lane == 0) {
            float kn = sqrtf(sq);
            float ob = osh[64], og = osh[65], os0 = osh[66], os1 = osh[67],
                  os2 = osh[68], ogm = osh[69];
            float beta  = fmaxf(ob, 0.f) + log1pf(expf(-fabsf(ob)));
            float g     = 1.f / (1.f + expf(-og));
            float mx    = fmaxf(os0, fmaxf(os1, os2));
            float e0 = expf(os0 - mx), e1 = expf(os1 - mx), e2 = expf(os2 - mx);
            float es = e0 + e1 + e2;
            float gamma = 1.f + fmaxf(ogm, 0.f) + log1pf(expf(-fabsf(ogm)));
            float* sc = ws + SCAL_OFF + b * 8;
            sc[0] = kn; sc[1] = beta; sc[2] = g;
            sc[3] = e0 / es; sc[4] = e1 / es; sc[5] = e2 / es;
            sc[6] = gamma;
        }
    }
}

// ---------- K2: score[b,n] = beta * dot(k, mem_row) / (kn*||mem_row|| + eps) ----------
__global__ __launch_bounds__(256) void k2(const float* __restrict__ mem,
                                          float* __restrict__ ws) {
    int b = blockIdx.x >> 5, chunk = blockIdx.x & 31;
    __shared__ float ks[64];
    __shared__ float kb[2];
    int tid = threadIdx.x;
    if (tid < 64) ks[tid] = ws[K_OFF + b * 64 + tid];
    if (tid == 64) kb[0] = ws[SCAL_OFF + b * 8 + 0];
    if (tid == 65) kb[1] = ws[SCAL_OFF + b * 8 + 1];
    __syncthreads();
    float kn = kb[0], beta = kb[1];
    int grp = tid >> 4, ll = tid & 15;
    float k0 = ks[ll * 4], k1v = ks[ll * 4 + 1], k2v = ks[ll * 4 + 2], k3v = ks[ll * 4 + 3];
    int row0 = chunk * 512;
    #pragma unroll 4
    for (int it = 0; it < 32; ++it) {
        int row = row0 + it * 16 + grp;
        float4 v = *reinterpret_cast<const float4*>(
            mem + ((size_t)b * N + row) * MDIM + ll * 4);
        float dot = v.x * k0 + v.y * k1v + v.z * k2v + v.w * k3v;
        float sq  = v.x * v.x + v.y * v.y + v.z * v.z + v.w * v.w;
        dot = rowsum16(dot);
        sq  = rowsum16(sq);
        if (ll == 0) {
            float denom = kn * sqrtf(sq) + EPSF;
            ws[SCORE_OFF + (size_t)b * N + row] = beta * (dot / denom);
        }
    }
}

// ---------- KW: softmax over N, interpolate, shift, sharpen, normalize -> w ----------
__global__ __launch_bounds__(1024) void kw(const float* __restrict__ w_prev,
                                           const float* __restrict__ ws,
                                           float* __restrict__ w_out) {
    int b = blockIdx.x;
    __shared__ float wg[N];     // w_g values (needed for the circular shift)
    __shared__ float red[16];
    int tid = threadIdx.x, wave = tid >> 6, lane = tid & 63;
    const float* sc = ws + SCORE_OFF + (size_t)b * N;
    const float* sl = ws + SCAL_OFF + b * 8;
    float g = sl[2], s0 = sl[3], s1 = sl[4], s2 = sl[5], gamma = sl[6];
    const float* wp = w_prev + (size_t)b * N;

    // pass 1: load scores into regs, block max
    float scv[16];
    float mx = -INFINITY;
    #pragma unroll
    for (int j = 0; j < 16; ++j) {
        scv[j] = sc[tid + 1024 * j];
        mx = fmaxf(mx, scv[j]);
    }
    #pragma unroll
    for (int off = 32; off > 0; off >>= 1) mx = fmaxf(mx, __shfl_xor(mx, off));
    if (lane == 0) red[wave] = mx;
    __syncthreads();
    mx = red[0];
    #pragma unroll
    for (int w2 = 1; w2 < 16; ++w2) mx = fmaxf(mx, red[w2]);
    __syncthreads();

    // pass 2: exp in regs, block sum
    float s = 0.f;
    #pragma unroll
    for (int j = 0; j < 16; ++j) {
        scv[j] = __expf(scv[j] - mx);
        s += scv[j];
    }
    #pragma unroll
    for (int off = 32; off > 0; off >>= 1) s += __shfl_xor(s, off);
    if (lane == 0) red[wave] = s;
    __syncthreads();
    s = red[0];
    #pragma unroll
    for (int w2 = 1; w2 < 16; ++w2) s += red[w2];
    float inv = 1.f / s;
    __syncthreads();

    // pass 3: w_g = g*w_c + (1-g)*w_prev -> LDS
    #pragma unroll
    for (int j = 0; j < 16; ++j) {
        int i = tid + 1024 * j;
        wg[i] = g * (scv[j] * inv) + (1.f - g) * wp[i];
    }
    __syncthreads();

    // pass 4: shift + pow into regs, block sum
    float pv[16];
    float sp = 0.f;
    #pragma unroll
    for (int j = 0; j < 16; ++j) {
        int i = tid + 1024 * j;
        float wt = s0 * wg[(i - 1) & (N - 1)] + s1 * wg[i] + s2 * wg[(i + 1) & (N - 1)];
        float p = __expf(gamma * __logf(wt));   // wt > 0; wt==0 -> -inf -> 0
        pv[j] = p;
        sp += p;
    }
    #pragma unroll
    for (int off = 32; off > 0; off >>= 1) sp += __shfl_xor(sp, off);
    if (lane == 0) red[wave] = sp;
    __syncthreads();
    float spTot = red[0];
    #pragma unroll
    for (int w2 = 1; w2 < 16; ++w2) spTot += red[w2];
    float invp = 1.f / (spTot + EPSF);

    // pass 5: write normalized w from regs
    #pragma unroll
    for (int j = 0; j < 16; ++j) {
        int i = tid + 1024 * j;
        w_out[(size_t)b * N + i] = pv[j] * invp;
    }
}

// ---------- KR: partial r = sum_n w[n] * mem[n, :] ----------
__global__ __launch_bounds__(256) void kr(const float* __restrict__ mem,
                                          const float* __restrict__ w,
                                          float* __restrict__ part) {
    int b = blockIdx.x >> 5, chunk = blockIdx.x & 31;
    int tid = threadIdx.x, grp = tid >> 4, ll = tid & 15;
    float4 acc = make_float4(0.f, 0.f, 0.f, 0.f);
    int row0 = chunk * 512;
    #pragma unroll 4
    for (int it = 0; it < 32; ++it) {
        int row = row0 + it * 16 + grp;
        float wv = w[(size_t)b * N + row];
        float4 v = *reinterpret_cast<const float4*>(
            mem + ((size_t)b * N + row) * MDIM + ll * 4);
        acc.x += wv * v.x; acc.y += wv * v.y; acc.z += wv * v.z; acc.w += wv * v.w;
    }
    __shared__ float lds[16][64];
    lds[grp][ll * 4 + 0] = acc.x;
    lds[grp][ll * 4 + 1] = acc.y;
    lds[grp][ll * 4 + 2] = acc.z;
    lds[grp][ll * 4 + 3] = acc.w;
    __syncthreads();
    if (tid < 64) {
        float sacc = 0.f;
        #pragma unroll
        for (int gi = 0; gi < 16; ++gi) sacc += lds[gi][tid];
        part[(size_t)blockIdx.x * 64 + tid] = sacc;
    }
}

// ---------- KRR: reduce partials -> r ----------
__global__ __launch_bounds__(64) void krr(const float* __restrict__ part,
                                          float* __restrict__ r) {
    int b = blockIdx.x, m = threadIdx.x;
    float s = 0.f;
    #pragma unroll
    for (int c = 0; c < 32; ++c) s += part[((size_t)b * 32 + c) * 64 + m];
    r[b * 64 + m] = s;
}

extern "C" void kernel_launch(void* const* d_in, const int* in_sizes, int n_in,
                              void* d_out, int out_size, void* d_ws, size_t ws_size,
                              hipStream_t stream) {
    const float* c      = (const float*)d_in[0];
    const float* w_prev = (const float*)d_in[1];
    const float* mem    = (const float*)d_in[2];
    const float* W      = (const float*)d_in[3];
    const float* bias   = (const float*)d_in[4];
    float* out = (float*)d_out;
    float* r_out = out;                 // B*M
    float* w_out = out + B * MDIM;      // B*N
    float* ws = (float*)d_ws;

    k1<<<B, 256, 0, stream>>>(c, W, bias, ws);
    k2<<<B * 32, 256, 0, stream>>>(mem, ws);
    kw<<<B, 1024, 0, stream>>>(w_prev, ws, w_out);
    kr<<<B * 32, 256, 0, stream>>>(mem, w_out, ws + PART_OFF);
    krr<<<B, 64, 0, stream>>>(ws + PART_OFF, r_out);
}

// Round 3
// 112.365 us; speedup vs baseline: 1.6412x; 1.0115x over previous
//
#include <hip/hip_runtime.h>
#include <math.h>

#define B 64
#define N 16384
#define MDIM 64
#define DDIM 512
#define EPSF 1e-16f

// ws float layout
#define K_OFF      0                      // B*64
#define SCAL_OFF   (B*64)                 // B*8: kn,beta,g,s0,s1,s2,gamma,pad
#define SCORE_OFF  (SCAL_OFF + B*8)       // B*N
#define PART_OFF   (SCORE_OFF + B*N)      // B*32*64

// 16-lane (DPP row) sum reduction: row_ror 8,4,2,1. All 16 lanes end with the sum.
__device__ __forceinline__ float rowsum16(float x) {
    float t;
    t = __int_as_float(__builtin_amdgcn_update_dpp(0, __float_as_int(x), 0x128, 0xF, 0xF, true)); x += t;
    t = __int_as_float(__builtin_amdgcn_update_dpp(0, __float_as_int(x), 0x124, 0xF, 0xF, true)); x += t;
    t = __int_as_float(__builtin_amdgcn_update_dpp(0, __float_as_int(x), 0x122, 0xF, 0xF, true)); x += t;
    t = __int_as_float(__builtin_amdgcn_update_dpp(0, __float_as_int(x), 0x121, 0xF, 0xF, true)); x += t;
    return x;
}

// ---------- K1: o = c@W.T + b, activations ----------
__global__ __launch_bounds__(256) void k1(const float* __restrict__ c,
                                          const float* __restrict__ W,
                                          const float* __restrict__ bias,
                                          float* __restrict__ ws) {
    int b = blockIdx.x;
    __shared__ float cs[DDIM];
    __shared__ float osh[72];
    int tid = threadIdx.x;
    for (int i = tid; i < DDIM; i += 256) cs[i] = c[b * DDIM + i];
    __syncthreads();
    int wave = tid >> 6, lane = tid & 63;
    for (int j = wave; j < MDIM + 6; j += 4) {
        const float* wr = W + (size_t)j * DDIM;
        float sum = 0.f;
        for (int d = lane; d < DDIM; d += 64) sum += cs[d] * wr[d];
        for (int off = 32; off > 0; off >>= 1) sum += __shfl_xor(sum, off);
        if (lane == 0) osh[j] = sum + bias[j];
    }
    __syncthreads();
    if (tid < 64) ws[K_OFF + b * 64 + tid] = osh[tid];
    if (wave == 0) {
        float v = osh[lane];
        float sq = v * v;
        for (int off = 32; off > 0; off >>= 1) sq += __shfl_xor(sq, off);
        if (lane == 0) {
            float kn = sqrtf(sq);
            float ob = osh[64], og = osh[65], os0 = osh[66], os1 = osh[67],
                  os2 = osh[68], ogm = osh[69];
            float beta  = fmaxf(ob, 0.f) + log1pf(expf(-fabsf(ob)));
            float g     = 1.f / (1.f + expf(-og));
            float mx    = fmaxf(os0, fmaxf(os1, os2));
            float e0 = expf(os0 - mx), e1 = expf(os1 - mx), e2 = expf(os2 - mx);
            float es = e0 + e1 + e2;
            float gamma = 1.f + fmaxf(ogm, 0.f) + log1pf(expf(-fabsf(ogm)));
            float* sc = ws + SCAL_OFF + b * 8;
            sc[0] = kn; sc[1] = beta; sc[2] = g;
            sc[3] = e0 / es; sc[4] = e1 / es; sc[5] = e2 / es;
            sc[6] = gamma;
        }
    }
}

// ---------- K2: score[b,n] = beta * dot(k, mem_row) / (kn*||mem_row|| + eps) ----------
__global__ __launch_bounds__(256) void k2(const float* __restrict__ mem,
                                          float* __restrict__ ws) {
    int b = blockIdx.x >> 5, chunk = blockIdx.x & 31;
    __shared__ float ks[64];
    __shared__ float kb[2];
    int tid = threadIdx.x;
    if (tid < 64) ks[tid] = ws[K_OFF + b * 64 + tid];
    if (tid == 64) kb[0] = ws[SCAL_OFF + b * 8 + 0];
    if (tid == 65) kb[1] = ws[SCAL_OFF + b * 8 + 1];
    __syncthreads();
    float kn = kb[0], beta = kb[1];
    int grp = tid >> 4, ll = tid & 15;
    float k0 = ks[ll * 4], k1v = ks[ll * 4 + 1], k2v = ks[ll * 4 + 2], k3v = ks[ll * 4 + 3];
    int row0 = chunk * 512;
    #pragma unroll 4
    for (int it = 0; it < 32; ++it) {
        int row = row0 + it * 16 + grp;
        float4 v = *reinterpret_cast<const float4*>(
            mem + ((size_t)b * N + row) * MDIM + ll * 4);
        float dot = v.x * k0 + v.y * k1v + v.z * k2v + v.w * k3v;
        float sq  = v.x * v.x + v.y * v.y + v.z * v.z + v.w * v.w;
        dot = rowsum16(dot);
        sq  = rowsum16(sq);
        if (ll == 0) {
            float denom = kn * sqrtf(sq) + EPSF;
            ws[SCORE_OFF + (size_t)b * N + row] = beta * (dot / denom);
        }
    }
}

// ---------- KW: softmax over N, interpolate, shift, sharpen, normalize -> w ----------
__global__ __launch_bounds__(1024) void kw(const float* __restrict__ w_prev,
                                           const float* __restrict__ ws,
                                           float* __restrict__ w_out) {
    int b = blockIdx.x;
    __shared__ float wg[N];     // w_g values (needed for the circular shift)
    __shared__ float red[16];
    int tid = threadIdx.x, wave = tid >> 6, lane = tid & 63;
    const float* sc = ws + SCORE_OFF + (size_t)b * N;
    const float* sl = ws + SCAL_OFF + b * 8;
    float g = sl[2], s0 = sl[3], s1 = sl[4], s2 = sl[5], gamma = sl[6];
    const float* wp = w_prev + (size_t)b * N;

    // pass 1: load scores into regs, block max
    float scv[16];
    float mx = -INFINITY;
    #pragma unroll
    for (int j = 0; j < 16; ++j) {
        scv[j] = sc[tid + 1024 * j];
        mx = fmaxf(mx, scv[j]);
    }
    #pragma unroll
    for (int off = 32; off > 0; off >>= 1) mx = fmaxf(mx, __shfl_xor(mx, off));
    if (lane == 0) red[wave] = mx;
    __syncthreads();
    mx = red[0];
    #pragma unroll
    for (int w2 = 1; w2 < 16; ++w2) mx = fmaxf(mx, red[w2]);
    __syncthreads();

    // pass 2: exp in regs, block sum
    float s = 0.f;
    #pragma unroll
    for (int j = 0; j < 16; ++j) {
        scv[j] = __expf(scv[j] - mx);
        s += scv[j];
    }
    #pragma unroll
    for (int off = 32; off > 0; off >>= 1) s += __shfl_xor(s, off);
    if (lane == 0) red[wave] = s;
    __syncthreads();
    s = red[0];
    #pragma unroll
    for (int w2 = 1; w2 < 16; ++w2) s += red[w2];
    float inv = 1.f / s;
    __syncthreads();

    // pass 3: w_g = g*w_c + (1-g)*w_prev -> LDS
    #pragma unroll
    for (int j = 0; j < 16; ++j) {
        int i = tid + 1024 * j;
        wg[i] = g * (scv[j] * inv) + (1.f - g) * wp[i];
    }
    __syncthreads();

    // pass 4: shift + pow into regs, block sum
    float pv[16];
    float sp = 0.f;
    #pragma unroll
    for (int j = 0; j < 16; ++j) {
        int i = tid + 1024 * j;
        float wt = s0 * wg[(i - 1) & (N - 1)] + s1 * wg[i] + s2 * wg[(i + 1) & (N - 1)];
        float p = __expf(gamma * __logf(wt));   // wt > 0; wt==0 -> -inf -> 0
        pv[j] = p;
        sp += p;
    }
    #pragma unroll
    for (int off = 32; off > 0; off >>= 1) sp += __shfl_xor(sp, off);
    if (lane == 0) red[wave] = sp;
    __syncthreads();
    float spTot = red[0];
    #pragma unroll
    for (int w2 = 1; w2 < 16; ++w2) spTot += red[w2];
    float invp = 1.f / (spTot + EPSF);

    // pass 5: write normalized w from regs
    #pragma unroll
    for (int j = 0; j < 16; ++j) {
        int i = tid + 1024 * j;
        w_out[(size_t)b * N + i] = pv[j] * invp;
    }
}

// ---------- KR: partial r = sum_n w[n] * mem[n, :] ----------
// Rows iterated in REVERSE: k2 (fully co-resident grid) finished each chunk at
// its tail, so the tail is the hottest region of Infinity Cache. Backward walk
// turns the re-read into L3 hits instead of the LRU-worst-case forward walk.
__global__ __launch_bounds__(256) void kr(const float* __restrict__ mem,
                                          const float* __restrict__ w,
                                          float* __restrict__ part) {
    int b = blockIdx.x >> 5, chunk = blockIdx.x & 31;
    int tid = threadIdx.x, grp = tid >> 4, ll = tid & 15;
    float4 acc = make_float4(0.f, 0.f, 0.f, 0.f);
    int row0 = chunk * 512;
    #pragma unroll 4
    for (int it = 31; it >= 0; --it) {
        int row = row0 + it * 16 + grp;
        float wv = w[(size_t)b * N + row];
        float4 v = *reinterpret_cast<const float4*>(
            mem + ((size_t)b * N + row) * MDIM + ll * 4);
        acc.x += wv * v.x; acc.y += wv * v.y; acc.z += wv * v.z; acc.w += wv * v.w;
    }
    __shared__ float lds[16][64];
    lds[grp][ll * 4 + 0] = acc.x;
    lds[grp][ll * 4 + 1] = acc.y;
    lds[grp][ll * 4 + 2] = acc.z;
    lds[grp][ll * 4 + 3] = acc.w;
    __syncthreads();
    if (tid < 64) {
        float sacc = 0.f;
        #pragma unroll
        for (int gi = 0; gi < 16; ++gi) sacc += lds[gi][tid];
        part[(size_t)blockIdx.x * 64 + tid] = sacc;
    }
}

// ---------- KRR: reduce partials -> r ----------
__global__ __launch_bounds__(64) void krr(const float* __restrict__ part,
                                          float* __restrict__ r) {
    int b = blockIdx.x, m = threadIdx.x;
    float s = 0.f;
    #pragma unroll
    for (int c = 0; c < 32; ++c) s += part[((size_t)b * 32 + c) * 64 + m];
    r[b * 64 + m] = s;
}

extern "C" void kernel_launch(void* const* d_in, const int* in_sizes, int n_in,
                              void* d_out, int out_size, void* d_ws, size_t ws_size,
                              hipStream_t stream) {
    const float* c      = (const float*)d_in[0];
    const float* w_prev = (const float*)d_in[1];
    const float* mem    = (const float*)d_in[2];
    const float* W      = (const float*)d_in[3];
    const float* bias   = (const float*)d_in[4];
    float* out = (float*)d_out;
    float* r_out = out;                 // B*M
    float* w_out = out + B * MDIM;      // B*N
    float* ws = (float*)d_ws;

    k1<<<B, 256, 0, stream>>>(c, W, bias, ws);
    k2<<<B * 32, 256, 0, stream>>>(mem, ws);
    kw<<<B, 1024, 0, stream>>>(w_prev, ws, w_out);
    kr<<<B * 32, 256, 0, stream>>>(mem, w_out, ws + PART_OFF);
    krr<<<B, 64, 0, stream>>>(ws + PART_OFF, r_out);
}